// Round 9
// baseline (2566.107 us; speedup 1.0000x reference)
//
#include <hip/hip_runtime.h>
#include <hip/hip_bf16.h>
#include <hip/hip_fp16.h>

constexpr int N_NODES = 100000;
constexpr int N_REL   = 3;
constexpr int N_EDGE  = 1600000;
constexpr int NCHUNK  = (N_NODES + 1023) / 1024;   // 98 (scan chunks)

// atomic-free degree counting geometry
constexpr int CCHUNK = 50;                 // edge chunks  -> 50*3*2 = 300 blocks
constexpr int CH     = N_EDGE / CCHUNK;    // 32000 edges per block
constexpr int SUBN   = 50000;              // nodes per LDS pass (50 KB byte counters)
constexpr int WPP    = SUBN / 4;           // 12500 packed words per pass
constexpr int CWORDS = N_NODES / 4;        // 25000 packed words per (chunk,rel,dir)

// two-level scatter geometry
constexpr int BSH  = 7;                    // bucket = node >> 7 (128 nodes/bucket)
constexpr int BNPB = 1 << BSH;             // 128
constexpr int NB   = (N_NODES + BNPB - 1) / BNPB;   // 782 buckets

typedef __attribute__((ext_vector_type(8))) short short8;
typedef __attribute__((ext_vector_type(4))) float f32x4;

__device__ inline ushort f2bf(float x) {            // round-to-nearest-even bf16
  unsigned u = __float_as_uint(x);
  unsigned r = u + 0x7FFFu + ((u >> 16) & 1u);
  return (ushort)(r >> 16);
}
__device__ inline float bf2f(ushort h) { return __uint_as_float(((unsigned)h) << 16); }

// ---------------- graph preprocessing (atomic-free counting) ----------------

__global__ __launch_bounds__(1024)
void count_kernel(const int* __restrict__ src, const int* __restrict__ dst,
                  uint* __restrict__ part) {
  int c = blockIdx.x, r = blockIdx.y, dir = blockIdx.z;
  const int* ids = (dir ? dst : src) + (size_t)r * N_EDGE + (size_t)c * CH;
  uint* p = part + ((size_t)(c * N_REL + r) * 2 + dir) * CWORDS;
  __shared__ uint hist[WPP];
  #pragma unroll
  for (int pass = 0; pass < 2; pass++) {
    int base = pass * SUBN;
    for (int i = threadIdx.x; i < WPP; i += 1024) hist[i] = 0u;
    __syncthreads();
    for (int e = (int)threadIdx.x; e < CH; e += 1024) {
      int ln = ids[e] - base;
      if ((unsigned)ln < (unsigned)SUBN)
        atomicAdd(&hist[ln >> 2], 1u << ((ln & 3) * 8));
    }
    __syncthreads();
    for (int i = threadIdx.x; i < WPP; i += 1024) p[pass * WPP + i] = hist[i];
    __syncthreads();
  }
}

__global__ void reduce_kernel(const uint* __restrict__ part,
                              int* __restrict__ deg_out, int* __restrict__ deg_in) {
  int i = blockIdx.x * 256 + threadIdx.x;       // over 3*CWORDS
  if (i >= N_REL * CWORDS) return;
  int r = i / CWORDS, w = i % CWORDS;
  uint aoe = 0, aoo = 0, aie = 0, aio = 0;
  for (int c = 0; c < CCHUNK; c++) {
    uint vo = part[((size_t)(c * N_REL + r) * 2 + 0) * CWORDS + w];
    uint vi = part[((size_t)(c * N_REL + r) * 2 + 1) * CWORDS + w];
    aoe += vo & 0x00FF00FFu; aoo += (vo >> 8) & 0x00FF00FFu;
    aie += vi & 0x00FF00FFu; aio += (vi >> 8) & 0x00FF00FFu;
  }
  int4 dout = make_int4((int)(aoe & 0xFFFFu), (int)(aoo & 0xFFFFu),
                        (int)(aoe >> 16),     (int)(aoo >> 16));
  int4 din  = make_int4((int)(aie & 0xFFFFu), (int)(aio & 0xFFFFu),
                        (int)(aie >> 16),     (int)(aio >> 16));
  *(int4*)&deg_out[(size_t)r * N_NODES + w * 4] = dout;
  *(int4*)&deg_in [(size_t)r * N_NODES + w * 4] = din;
}

__global__ void inv_kernel(const int* __restrict__ deg_out, const int* __restrict__ deg_in,
                           float* __restrict__ inv_out, float* __restrict__ inv_in) {
  int i = blockIdx.x * blockDim.x + threadIdx.x;
  if (i >= N_REL * N_NODES) return;
  inv_out[i] = rsqrtf(fmaxf((float)deg_out[i], 1.0f));
  inv_in[i]  = rsqrtf(fmaxf((float)deg_in[i],  1.0f));
}

__global__ void scan1_kernel(const int* __restrict__ deg_in, int* __restrict__ excl,
                             int* __restrict__ part) {
  int r = blockIdx.y;
  int i = blockIdx.x * 1024 + threadIdx.x;
  int v = (i < N_NODES) ? deg_in[r * N_NODES + i] : 0;
  __shared__ int sm[1024];
  sm[threadIdx.x] = v;
  __syncthreads();
  for (int off = 1; off < 1024; off <<= 1) {
    int t = (threadIdx.x >= (unsigned)off) ? sm[threadIdx.x - off] : 0;
    __syncthreads();
    sm[threadIdx.x] += t;
    __syncthreads();
  }
  if (i < N_NODES) excl[r * N_NODES + i] = sm[threadIdx.x] - v;
  if (threadIdx.x == 1023) part[r * NCHUNK + blockIdx.x] = sm[1023];
}

__global__ void scan2_kernel(int* __restrict__ part) {
  int r = blockIdx.x;
  int* p = part + r * NCHUNK;
  __shared__ int sm[128];
  int tid = threadIdx.x;
  int v = (tid < NCHUNK) ? p[tid] : 0;
  sm[tid] = v;
  __syncthreads();
  for (int off = 1; off < 128; off <<= 1) {
    int t = (tid >= off) ? sm[tid - off] : 0;
    __syncthreads();
    sm[tid] += t;
    __syncthreads();
  }
  if (tid < NCHUNK) p[tid] = sm[tid] - v;
}

__global__ void scan3_kernel(const int* __restrict__ excl, const int* __restrict__ part,
                             int* __restrict__ row_off) {
  int r = blockIdx.y;
  int i = blockIdx.x * 1024 + threadIdx.x;
  if (i < N_NODES) row_off[r * (N_NODES + 1) + i] = excl[r * N_NODES + i] + part[r * NCHUNK + (i >> 10)];
  if (i == N_NODES) row_off[r * (N_NODES + 1) + N_NODES] = N_EDGE;
}

// ---------------- two-level scatter, fully atomic-free level 1 ----------------

__global__ __launch_bounds__(64)
void boff_kernel(const uint* __restrict__ cpart, int* __restrict__ boff) {
  int b = blockIdx.x, r = blockIdx.y;
  int lane = threadIdx.x;                     // 0..63 (lanes 32-63 duplicate 0-31)
  __shared__ int cnt_l[CCHUNK];
  for (int c = 0; c < CCHUNK; c++) {
    int w = b * 32 + (lane & 31);
    uint v = 0;
    if (w < CWORDS)
      v = cpart[((size_t)(c * N_REL + r) * 2 + 1) * CWORDS + w];   // dir=1: dst
    int s = (int)((v & 0xFFu) + ((v >> 8) & 0xFFu) + ((v >> 16) & 0xFFu) + (v >> 24));
    #pragma unroll
    for (int k = 16; k >= 1; k >>= 1) s += __shfl_xor(s, k);
    if (lane == 0) cnt_l[c] = s;
  }
  __syncthreads();
  if (lane == 0) {
    int run = 0;
    for (int c = 0; c < CCHUNK; c++) { int t = cnt_l[c]; cnt_l[c] = run; run += t; }
  }
  __syncthreads();
  for (int c = lane; c < CCHUNK; c += 64)
    boff[((size_t)c * N_REL + r) * NB + b] = cnt_l[c];
}

__global__ __launch_bounds__(1024)
void bin2_kernel(const int* __restrict__ src, const int* __restrict__ dst,
                 const int* __restrict__ row_off, const int* __restrict__ boff,
                 int2* __restrict__ binned) {
  int c = blockIdx.x, r = blockIdx.y;
  __shared__ int cur[NB];
  for (int j = threadIdx.x; j < NB; j += 1024)
    cur[j] = row_off[r * (N_NODES + 1) + (j << BSH)] + boff[((size_t)c * N_REL + r) * NB + j];
  __syncthreads();
  const int* sp = src + (size_t)r * N_EDGE + (size_t)c * CH;
  const int* dp = dst + (size_t)r * N_EDGE + (size_t)c * CH;
  int2* bp = binned + (size_t)r * N_EDGE;
  for (int e = (int)threadIdx.x; e < CH; e += 1024) {
    int s = sp[e], d = dp[e];
    int slot = atomicAdd(&cur[d >> BSH], 1);
    bp[slot] = make_int2(s, d);
  }
}

__global__ __launch_bounds__(256)
void scatter2_kernel(const int2* __restrict__ binned, const int* __restrict__ row_off,
                     const float* __restrict__ inv_out, const float* __restrict__ inv_in,
                     float2* __restrict__ sorted_sc) {
  int b = blockIdx.x, r = blockIdx.y;
  int node0 = b << BSH;
  int node1 = min(node0 + BNPB, N_NODES);
  const int* ro = row_off + r * (N_NODES + 1);
  int base = ro[node0];
  int m    = ro[node1] - base;
  __shared__ int cur[BNPB];
  for (int j = threadIdx.x; j < node1 - node0; j += 256)
    cur[j] = ro[node0 + j] - base;
  __syncthreads();
  const int2* bp = binned + (size_t)r * N_EDGE + base;
  float2* op = sorted_sc + (size_t)r * N_EDGE + base;
  const float* ivo = inv_out + r * N_NODES;
  const float* ivi = inv_in  + r * N_NODES;
  for (int i = threadIdx.x; i < m; i += 256) {
    int2 rec = bp[i];
    int pos = atomicAdd(&cur[rec.y - node0], 1);
    float coef = ivo[rec.x] * ivi[rec.y];
    op[pos] = make_float2(__int_as_float(rec.x), coef);
  }
}

// per-layer weight preconvert: W[k][c] fp32 -> transposed hi/lo bf16 planes Wt[c][k]
__global__ void convw_kernel(const float* __restrict__ W, ushort* __restrict__ Wh,
                             ushort* __restrict__ Wl, int DOv) {
  int idx = blockIdx.x * 256 + threadIdx.x;
  if (idx >= 384 * DOv) return;
  int k = idx / DOv, c = idx % DOv;
  float v = W[idx];
  ushort hh = f2bf(v);
  Wh[c * 384 + k] = hh;
  Wl[c * 384 + k] = f2bf(v - bf2f(hh));
}

// x fp32 [N][128] -> fp16 [N][128]
__global__ void convx_kernel(const float* __restrict__ x, ushort* __restrict__ x16) {
  int i = blockIdx.x * 256 + threadIdx.x;      // one float4 group each
  if (i >= N_NODES * 32) return;
  f32x4 v = ((const f32x4*)x)[i];
  __half2 h0 = __floats2half2_rn(v.x, v.y);
  __half2 h1 = __floats2half2_rn(v.z, v.w);
  uint2 o;
  o.x = *(const unsigned*)&h0;
  o.y = *(const unsigned*)&h1;
  ((uint2*)x16)[i] = o;
}

// ---------------- fused per-layer kernel: agg (LDS A-tile) + bf16x3 GEMM ----

// Phase A (per rel): each wave aggregates 16 dst nodes (fp32 edge accum, fp16
// h gather — bit-identical to the old agg) and writes bf16 hi/lo A-tiles to
// LDS. Phase B: staged-W bf16x3 MFMA with A already in LDS. Eliminates the
// 150MB plane write + 307MB plane read per layer (the 3.7TB/s-limited stream).
// LDS tiles are flat with XOR swizzle (^((row&7)<<3) in ushort units): 2-way
// bank conflicts only (free). 48KB LDS -> 3 blocks/CU.
template<int P>
__device__ inline void agg_pairs(const float2* __restrict__ scp, const uint2* __restrict__ hp,
                                 int e, int sub, int l32, f32x4& acc) {
  float2 q[P];
  #pragma unroll
  for (int j = 0; j < P; j++) q[j] = scp[e + 2 * j + sub];
  uint2 v[P];
  #pragma unroll
  for (int j = 0; j < P; j++) v[j] = hp[(size_t)__float_as_int(q[j].x) * 32 + l32];
  #pragma unroll
  for (int j = 0; j < P; j++) {
    __half2 h0 = *(const __half2*)&v[j].x;
    __half2 h1 = *(const __half2*)&v[j].y;
    float2 f0 = __half22float2(h0);
    float2 f1 = __half22float2(h1);
    acc.x = fmaf(q[j].y, f0.x, acc.x);
    acc.y = fmaf(q[j].y, f0.y, acc.y);
    acc.z = fmaf(q[j].y, f1.x, acc.z);
    acc.w = fmaf(q[j].y, f1.y, acc.w);
  }
}

template<int DO, bool F16OUT>
__launch_bounds__(256)
__global__ void fused_kernel(const ushort* __restrict__ h, const float2* __restrict__ sc,
                             const int* __restrict__ row_off,
                             const ushort* __restrict__ Wh, const ushort* __restrict__ Wl,
                             const float* __restrict__ b, float* __restrict__ out,
                             ushort* __restrict__ out16, int apply_relu) {
  constexpr int NCT = DO / 16;
  __shared__ ushort As_hi[64 * 128], As_lo[64 * 128];       // A tile, XOR-swizzled
  __shared__ ushort Bs_hi[DO * 32],  Bs_lo[DO * 32];        // W chunk, XOR-swizzled
  int tid  = threadIdx.x;
  int wave = tid >> 6, lane = tid & 63;
  int sub  = lane >> 5, l32 = lane & 31;
  int quad = lane >> 4, m16 = lane & 15;
  int n0 = blockIdx.x * 64;
  const uint2* hp = (const uint2*)h;

  f32x4 acc[NCT];
  #pragma unroll
  for (int ct = 0; ct < NCT; ct++) acc[ct] = (f32x4){0.f, 0.f, 0.f, 0.f};

  for (int r = 0; r < N_REL; r++) {
    // ---- phase A: aggregate this block's 64 nodes for rel r into LDS ----
    const int* ro = row_off + r * (N_NODES + 1);
    const float2* scp = sc + (size_t)r * N_EDGE;
    for (int t = 0; t < 16; t++) {
      int row  = wave * 16 + t;
      int node = n0 + row;
      f32x4 a = (f32x4){0.f, 0.f, 0.f, 0.f};
      if (node < N_NODES) {
        int beg = ro[node], end = ro[node + 1];
        int e = beg;
        while (e + 16 <= end) { agg_pairs<8>(scp, hp, e, sub, l32, a); e += 16; }
        if (e + 8 <= end)     { agg_pairs<4>(scp, hp, e, sub, l32, a); e += 8; }
        if (e + 4 <= end)     { agg_pairs<2>(scp, hp, e, sub, l32, a); e += 4; }
        if (e + 2 <= end)     { agg_pairs<1>(scp, hp, e, sub, l32, a); e += 2; }
        if (e < end && sub == 0) {
          float2 q = scp[e];
          uint2 v = hp[(size_t)__float_as_int(q.x) * 32 + l32];
          __half2 h0 = *(const __half2*)&v.x;
          __half2 h1 = *(const __half2*)&v.y;
          float2 f0 = __half22float2(h0);
          float2 f1 = __half22float2(h1);
          a.x = fmaf(q.y, f0.x, a.x);
          a.y = fmaf(q.y, f0.y, a.y);
          a.z = fmaf(q.y, f1.x, a.z);
          a.w = fmaf(q.y, f1.y, a.w);
        }
      }
      a.x += __shfl_xor(a.x, 32);
      a.y += __shfl_xor(a.y, 32);
      a.z += __shfl_xor(a.z, 32);
      a.w += __shfl_xor(a.w, 32);
      float a0 = (sub == 0) ? a.x : a.z;
      float a1 = (sub == 0) ? a.y : a.w;
      ushort2 hi, lo;
      hi.x = f2bf(a0); lo.x = f2bf(a0 - bf2f(hi.x));
      hi.y = f2bf(a1); lo.y = f2bf(a1 - bf2f(hi.y));
      int col = l32 * 4 + sub * 2;
      int idx = (row * 128 + col) ^ ((row & 7) << 3);     // swizzled, ushort2-aligned
      *(ushort2*)&As_hi[idx] = hi;
      *(ushort2*)&As_lo[idx] = lo;
    }
    // no sync needed for As: each wave reads only its own 16 rows in phase B.

    // ---- phase B: 4 x 32-k MFMA chunks over this rel's A columns ----
    for (int kc = 0; kc < 128; kc += 32) {
      __syncthreads();                       // Bs free (prev chunk's MFMAs done)
      #pragma unroll
      for (int it = 0; it < DO / 64; it++) {
        int idx = it * 256 + tid;            // 0..DO*4-1
        int n = idx >> 2, kq = (idx & 3) * 8;
        int bi = (n * 32 + kq) ^ ((n & 7) << 3);          // swizzled, 8-aligned
        *(uint4*)&Bs_hi[bi] = *(const uint4*)(Wh + (size_t)n * 384 + r * 128 + kc + kq);
        *(uint4*)&Bs_lo[bi] = *(const uint4*)(Wl + (size_t)n * 384 + r * 128 + kc + kq);
      }
      __syncthreads();                       // Bs ready

      int arow = wave * 16 + m16;
      int ai = (arow * 128 + kc + quad * 8) ^ ((arow & 7) << 3);
      short8 ah = *(const short8*)&As_hi[ai];
      short8 al = *(const short8*)&As_lo[ai];
      #pragma unroll
      for (int ct = 0; ct < NCT; ct++) {
        int n = ct * 16 + m16;
        int bi = (n * 32 + quad * 8) ^ ((n & 7) << 3);
        short8 bh = *(const short8*)&Bs_hi[bi];
        short8 bl = *(const short8*)&Bs_lo[bi];
        acc[ct] = __builtin_amdgcn_mfma_f32_16x16x32_bf16(ah, bh, acc[ct], 0, 0, 0);
        acc[ct] = __builtin_amdgcn_mfma_f32_16x16x32_bf16(ah, bl, acc[ct], 0, 0, 0);
        acc[ct] = __builtin_amdgcn_mfma_f32_16x16x32_bf16(al, bh, acc[ct], 0, 0, 0);
      }
    }
    __syncthreads();                         // As/Bs free for next rel
  }

  // ---- epilogue: C/D layout col=lane&15, row=quad*4+reg ----
  #pragma unroll
  for (int ct = 0; ct < NCT; ct++) {
    int col = ct * 16 + m16;
    float bs = b[col] + b[DO + col] + b[2 * DO + col];
    #pragma unroll
    for (int v = 0; v < 4; v++) {
      int row = n0 + wave * 16 + quad * 4 + v;
      if (row < N_NODES) {
        float o = acc[ct][v] + bs;
        if (apply_relu) o = fmaxf(o, 0.f);
        if (F16OUT) {
          __half ho = __float2half_rn(o);
          out16[(size_t)row * DO + col] = *(const ushort*)&ho;
        } else {
          out[(size_t)row * DO + col] = o;
        }
      }
    }
  }
}

// ---------------- launch ----------------

extern "C" void kernel_launch(void* const* d_in, const int* in_sizes, int n_in,
                              void* d_out, int out_size, void* d_ws, size_t ws_size,
                              hipStream_t stream) {
  const float* x   = (const float*)d_in[0];
  const int*   src = (const int*)d_in[1];
  const int*   dst = (const int*)d_in[2];
  const float* Wl6[6]; const float* bl[6];
  for (int i = 0; i < 6; i++) { Wl6[i] = (const float*)d_in[3 + 2*i]; bl[i] = (const float*)d_in[4 + 2*i]; }

  char* ws = (char*)d_ws;
  size_t off = 0;
  auto take = [&](size_t bytes) -> char* {
    char* p = ws + off;
    off = (off + bytes + 255) & ~(size_t)255;
    return p;
  };
  ushort* h16a    = (ushort*)take((size_t)N_NODES * 128 * 2);   // fp16 hidden (ping)
  ushort* h16b    = (ushort*)take((size_t)N_NODES * 128 * 2);   // fp16 hidden (pong)
  int*    deg     = (int*)  take((size_t)2 * N_REL * N_NODES * 4);
  int*    deg_out = deg;
  int*    deg_in  = deg + N_REL * N_NODES;
  float*  inv_out = (float*)take((size_t)N_REL * N_NODES * 4);
  float*  inv_in  = (float*)take((size_t)N_REL * N_NODES * 4);
  int*    row_off = (int*)  take((size_t)N_REL * (N_NODES + 1) * 4);
  int*    part    = (int*)  take((size_t)N_REL * NCHUNK * 4);
  int*    boff    = (int*)  take((size_t)CCHUNK * N_REL * NB * 4);   // 469 KB
  float2* s_sc    = (float2*)take((size_t)N_REL * N_EDGE * 8);       // 38.4 MB
  ushort* Wt      = (ushort*)take((size_t)6 * 384 * 128 * 2 * 2);    // hi|lo per layer
  int*    excl    = (int*)  take((size_t)N_REL * N_NODES * 4);       // 1.2 MB
  uint*   cpart   = (uint*) take((size_t)CCHUNK * N_REL * 2 * CWORDS * 4);  // 30 MB
  int2*   binned  = (int2*) take((size_t)N_REL * N_EDGE * 8);        // 38.4 MB
  (void)ws_size; (void)in_sizes; (void)n_in; (void)out_size;

  const int nblocks = (N_REL * N_NODES + 255) / 256;

  count_kernel<<<dim3(CCHUNK, N_REL, 2), 1024, 0, stream>>>(src, dst, cpart);
  reduce_kernel<<<(N_REL * CWORDS + 255) / 256, 256, 0, stream>>>(cpart, deg_out, deg_in);
  inv_kernel<<<nblocks, 256, 0, stream>>>(deg_out, deg_in, inv_out, inv_in);
  scan1_kernel<<<dim3(NCHUNK, 3), 1024, 0, stream>>>(deg_in, excl, part);
  scan2_kernel<<<3, 128, 0, stream>>>(part);
  scan3_kernel<<<dim3(NCHUNK + 1, 3), 1024, 0, stream>>>(excl, part, row_off);
  boff_kernel<<<dim3(NB, N_REL), 64, 0, stream>>>(cpart, boff);
  bin2_kernel<<<dim3(CCHUNK, N_REL), 1024, 0, stream>>>(src, dst, row_off, boff, binned);
  scatter2_kernel<<<dim3(NB, N_REL), 256, 0, stream>>>(binned, row_off, inv_out, inv_in, s_sc);

  convx_kernel<<<(N_NODES * 32 + 255) / 256, 256, 0, stream>>>(x, h16a);

  ushort* Wh[6]; ushort* Wlo[6];
  {
    size_t woff = 0;
    for (int L = 0; L < 6; L++) {
      int DOv = (L < 5) ? 128 : 64;
      Wh[L]  = Wt + woff;  woff += (size_t)384 * DOv;
      Wlo[L] = Wt + woff;  woff += (size_t)384 * DOv;
      convw_kernel<<<(384 * DOv + 255) / 256, 256, 0, stream>>>(Wl6[L], Wh[L], Wlo[L], DOv);
    }
  }

  const int mtiles = (N_NODES + 63) / 64;    // 1563
  ushort* hin  = h16a;
  ushort* hout = h16b;
  for (int L = 0; L < 6; L++) {
    if (L < 5) {
      fused_kernel<128, true><<<mtiles, 256, 0, stream>>>(hin, s_sc, row_off,
                                                          Wh[L], Wlo[L], bl[L],
                                                          nullptr, hout, 1);
      ushort* t = hin; hin = hout; hout = t;
    } else {
      fused_kernel<64, false><<<mtiles, 256, 0, stream>>>(hin, s_sc, row_off,
                                                          Wh[L], Wlo[L], bl[L],
                                                          (float*)d_out, nullptr, 0);
    }
  }
}

// Round 10
// 1738.725 us; speedup vs baseline: 1.4759x; 1.4759x over previous
//
#include <hip/hip_runtime.h>
#include <hip/hip_bf16.h>
#include <hip/hip_fp16.h>

constexpr int N_NODES = 100000;
constexpr int N_REL   = 3;
constexpr int N_EDGE  = 1600000;
constexpr int NCHUNK  = (N_NODES + 1023) / 1024;   // 98 (scan chunks)

// atomic-free degree counting geometry
constexpr int CCHUNK = 50;                 // edge chunks  -> 50*3*2 = 300 blocks
constexpr int CH     = N_EDGE / CCHUNK;    // 32000 edges per block
constexpr int SUBN   = 50000;              // nodes per LDS pass (50 KB byte counters)
constexpr int WPP    = SUBN / 4;           // 12500 packed words per pass
constexpr int CWORDS = N_NODES / 4;        // 25000 packed words per (chunk,rel,dir)

// two-level scatter geometry
constexpr int BSH  = 7;                    // bucket = node >> 7 (128 nodes/bucket)
constexpr int BNPB = 1 << BSH;             // 128
constexpr int NB   = (N_NODES + BNPB - 1) / BNPB;   // 782 buckets

typedef __attribute__((ext_vector_type(8))) short short8;
typedef __attribute__((ext_vector_type(4))) float f32x4;

__device__ inline ushort f2bf(float x) {            // round-to-nearest-even bf16
  unsigned u = __float_as_uint(x);
  unsigned r = u + 0x7FFFu + ((u >> 16) & 1u);
  return (ushort)(r >> 16);
}
__device__ inline float bf2f(ushort h) { return __uint_as_float(((unsigned)h) << 16); }

// ---------------- graph preprocessing (atomic-free counting) ----------------

// Byte-packed LDS histogram: 4 node-counters per int word. 50KB LDS covers
// 50K nodes -> 2 passes over this block's 32K-edge chunk. 300 blocks.
__global__ __launch_bounds__(1024)
void count_kernel(const int* __restrict__ src, const int* __restrict__ dst,
                  uint* __restrict__ part) {
  int c = blockIdx.x, r = blockIdx.y, dir = blockIdx.z;
  const int* ids = (dir ? dst : src) + (size_t)r * N_EDGE + (size_t)c * CH;
  uint* p = part + ((size_t)(c * N_REL + r) * 2 + dir) * CWORDS;
  __shared__ uint hist[WPP];
  #pragma unroll
  for (int pass = 0; pass < 2; pass++) {
    int base = pass * SUBN;
    for (int i = threadIdx.x; i < WPP; i += 1024) hist[i] = 0u;
    __syncthreads();
    for (int e = (int)threadIdx.x; e < CH; e += 1024) {
      int ln = ids[e] - base;
      if ((unsigned)ln < (unsigned)SUBN)
        atomicAdd(&hist[ln >> 2], 1u << ((ln & 3) * 8));
    }
    __syncthreads();
    for (int i = threadIdx.x; i < WPP; i += 1024) p[pass * WPP + i] = hist[i];
    __syncthreads();
  }
}

// SWAR reduce of packed byte partials: 16-bit lanes (50*255 = 12750 < 65536).
__global__ void reduce_kernel(const uint* __restrict__ part,
                              int* __restrict__ deg_out, int* __restrict__ deg_in) {
  int i = blockIdx.x * 256 + threadIdx.x;       // over 3*CWORDS
  if (i >= N_REL * CWORDS) return;
  int r = i / CWORDS, w = i % CWORDS;
  uint aoe = 0, aoo = 0, aie = 0, aio = 0;
  for (int c = 0; c < CCHUNK; c++) {
    uint vo = part[((size_t)(c * N_REL + r) * 2 + 0) * CWORDS + w];
    uint vi = part[((size_t)(c * N_REL + r) * 2 + 1) * CWORDS + w];
    aoe += vo & 0x00FF00FFu; aoo += (vo >> 8) & 0x00FF00FFu;
    aie += vi & 0x00FF00FFu; aio += (vi >> 8) & 0x00FF00FFu;
  }
  int4 dout = make_int4((int)(aoe & 0xFFFFu), (int)(aoo & 0xFFFFu),
                        (int)(aoe >> 16),     (int)(aoo >> 16));
  int4 din  = make_int4((int)(aie & 0xFFFFu), (int)(aio & 0xFFFFu),
                        (int)(aie >> 16),     (int)(aio >> 16));
  *(int4*)&deg_out[(size_t)r * N_NODES + w * 4] = dout;
  *(int4*)&deg_in [(size_t)r * N_NODES + w * 4] = din;
}

__global__ void inv_kernel(const int* __restrict__ deg_out, const int* __restrict__ deg_in,
                           float* __restrict__ inv_out, float* __restrict__ inv_in) {
  int i = blockIdx.x * blockDim.x + threadIdx.x;
  if (i >= N_REL * N_NODES) return;
  inv_out[i] = rsqrtf(fmaxf((float)deg_out[i], 1.0f));
  inv_in[i]  = rsqrtf(fmaxf((float)deg_in[i],  1.0f));
}

__global__ void scan1_kernel(const int* __restrict__ deg_in, int* __restrict__ excl,
                             int* __restrict__ part) {
  int r = blockIdx.y;
  int i = blockIdx.x * 1024 + threadIdx.x;
  int v = (i < N_NODES) ? deg_in[r * N_NODES + i] : 0;
  __shared__ int sm[1024];
  sm[threadIdx.x] = v;
  __syncthreads();
  for (int off = 1; off < 1024; off <<= 1) {
    int t = (threadIdx.x >= (unsigned)off) ? sm[threadIdx.x - off] : 0;
    __syncthreads();
    sm[threadIdx.x] += t;
    __syncthreads();
  }
  if (i < N_NODES) excl[r * N_NODES + i] = sm[threadIdx.x] - v;
  if (threadIdx.x == 1023) part[r * NCHUNK + blockIdx.x] = sm[1023];
}

__global__ void scan2_kernel(int* __restrict__ part) {
  int r = blockIdx.x;
  int* p = part + r * NCHUNK;
  __shared__ int sm[128];
  int tid = threadIdx.x;
  int v = (tid < NCHUNK) ? p[tid] : 0;
  sm[tid] = v;
  __syncthreads();
  for (int off = 1; off < 128; off <<= 1) {
    int t = (tid >= off) ? sm[tid - off] : 0;
    __syncthreads();
    sm[tid] += t;
    __syncthreads();
  }
  if (tid < NCHUNK) p[tid] = sm[tid] - v;
}

__global__ void scan3_kernel(const int* __restrict__ excl, const int* __restrict__ part,
                             int* __restrict__ row_off) {
  int r = blockIdx.y;
  int i = blockIdx.x * 1024 + threadIdx.x;
  if (i < N_NODES) row_off[r * (N_NODES + 1) + i] = excl[r * N_NODES + i] + part[r * NCHUNK + (i >> 10)];
  if (i == N_NODES) row_off[r * (N_NODES + 1) + N_NODES] = N_EDGE;
}

// ---------------- two-level scatter, fully atomic-free level 1 ----------------

__global__ __launch_bounds__(64)
void boff_kernel(const uint* __restrict__ cpart, int* __restrict__ boff) {
  int b = blockIdx.x, r = blockIdx.y;
  int lane = threadIdx.x;                     // 0..63 (lanes 32-63 duplicate 0-31)
  __shared__ int cnt_l[CCHUNK];
  for (int c = 0; c < CCHUNK; c++) {
    int w = b * 32 + (lane & 31);
    uint v = 0;
    if (w < CWORDS)
      v = cpart[((size_t)(c * N_REL + r) * 2 + 1) * CWORDS + w];   // dir=1: dst
    int s = (int)((v & 0xFFu) + ((v >> 8) & 0xFFu) + ((v >> 16) & 0xFFu) + (v >> 24));
    #pragma unroll
    for (int k = 16; k >= 1; k >>= 1) s += __shfl_xor(s, k);
    if (lane == 0) cnt_l[c] = s;
  }
  __syncthreads();
  if (lane == 0) {
    int run = 0;
    for (int c = 0; c < CCHUNK; c++) { int t = cnt_l[c]; cnt_l[c] = run; run += t; }
  }
  __syncthreads();
  for (int c = lane; c < CCHUNK; c += 64)
    boff[((size_t)c * N_REL + r) * NB + b] = cnt_l[c];
}

__global__ __launch_bounds__(1024)
void bin2_kernel(const int* __restrict__ src, const int* __restrict__ dst,
                 const int* __restrict__ row_off, const int* __restrict__ boff,
                 int2* __restrict__ binned) {
  int c = blockIdx.x, r = blockIdx.y;
  __shared__ int cur[NB];
  for (int j = threadIdx.x; j < NB; j += 1024)
    cur[j] = row_off[r * (N_NODES + 1) + (j << BSH)] + boff[((size_t)c * N_REL + r) * NB + j];
  __syncthreads();
  const int* sp = src + (size_t)r * N_EDGE + (size_t)c * CH;
  const int* dp = dst + (size_t)r * N_EDGE + (size_t)c * CH;
  int2* bp = binned + (size_t)r * N_EDGE;
  for (int e = (int)threadIdx.x; e < CH; e += 1024) {
    int s = sp[e], d = dp[e];
    int slot = atomicAdd(&cur[d >> BSH], 1);
    bp[slot] = make_int2(s, d);
  }
}

__global__ __launch_bounds__(256)
void scatter2_kernel(const int2* __restrict__ binned, const int* __restrict__ row_off,
                     const float* __restrict__ inv_out, const float* __restrict__ inv_in,
                     float2* __restrict__ sorted_sc) {
  int b = blockIdx.x, r = blockIdx.y;
  int node0 = b << BSH;
  int node1 = min(node0 + BNPB, N_NODES);
  const int* ro = row_off + r * (N_NODES + 1);
  int base = ro[node0];
  int m    = ro[node1] - base;
  __shared__ int cur[BNPB];
  for (int j = threadIdx.x; j < node1 - node0; j += 256)
    cur[j] = ro[node0 + j] - base;
  __syncthreads();
  const int2* bp = binned + (size_t)r * N_EDGE + base;
  float2* op = sorted_sc + (size_t)r * N_EDGE + base;
  const float* ivo = inv_out + r * N_NODES;
  const float* ivi = inv_in  + r * N_NODES;
  for (int i = threadIdx.x; i < m; i += 256) {
    int2 rec = bp[i];
    int pos = atomicAdd(&cur[rec.y - node0], 1);
    float coef = ivo[rec.x] * ivi[rec.y];
    op[pos] = make_float2(__int_as_float(rec.x), coef);
  }
}

// per-layer weight preconvert: W[k][c] fp32 -> transposed hi/lo bf16 planes Wt[c][k]
__global__ void convw_kernel(const float* __restrict__ W, ushort* __restrict__ Wh,
                             ushort* __restrict__ Wl, int DOv) {
  int idx = blockIdx.x * 256 + threadIdx.x;
  if (idx >= 384 * DOv) return;
  int k = idx / DOv, c = idx % DOv;
  float v = W[idx];
  ushort hh = f2bf(v);
  Wh[c * 384 + k] = hh;
  Wl[c * 384 + k] = f2bf(v - bf2f(hh));
}

// x fp32 [N][128] -> fp16 [N][128]
__global__ void convx_kernel(const float* __restrict__ x, ushort* __restrict__ x16) {
  int i = blockIdx.x * 256 + threadIdx.x;      // one float4 group each
  if (i >= N_NODES * 32) return;
  f32x4 v = ((const f32x4*)x)[i];
  __half2 h0 = __floats2half2_rn(v.x, v.y);
  __half2 h1 = __floats2half2_rn(v.z, v.w);
  uint2 o;
  o.x = *(const unsigned*)&h0;
  o.y = *(const unsigned*)&h1;
  ((uint2*)x16)[i] = o;
}

// ---------------- per-layer kernels ----------------

// Gather-first: acc[n][r*128+c] = sum coef_e * h[src_e][c] (fp32 accumulate),
// h stored fp16. Output: ONE fp16 plane (A is fp16-accurate anyway; halves the
// agg write AND the gemm A-read vs bf16 hi/lo planes — both streams ride the
// ~3.7TB/s L2-miss service rate that bounds this phase).
template<int P>
__device__ inline void agg_pairs(const float2* __restrict__ scp, const uint2* __restrict__ hp,
                                 int e, int sub, int l32, f32x4& acc) {
  float2 q[P];
  #pragma unroll
  for (int j = 0; j < P; j++) q[j] = scp[e + 2 * j + sub];
  uint2 v[P];
  #pragma unroll
  for (int j = 0; j < P; j++) v[j] = hp[(size_t)__float_as_int(q[j].x) * 32 + l32];
  #pragma unroll
  for (int j = 0; j < P; j++) {
    __half2 h0 = *(const __half2*)&v[j].x;
    __half2 h1 = *(const __half2*)&v[j].y;
    float2 f0 = __half22float2(h0);
    float2 f1 = __half22float2(h1);
    acc.x = fmaf(q[j].y, f0.x, acc.x);
    acc.y = fmaf(q[j].y, f0.y, acc.y);
    acc.z = fmaf(q[j].y, f1.x, acc.z);
    acc.w = fmaf(q[j].y, f1.y, acc.w);
  }
}

__launch_bounds__(256)
__global__ void agg_kernel(const ushort* __restrict__ h, const float2* __restrict__ sc,
                           const int* __restrict__ row_off,
                           ushort* __restrict__ agg16) {
  int r    = blockIdx.y;
  int node = blockIdx.x * 4 + ((int)threadIdx.x >> 6);
  int lane = (int)threadIdx.x & 63;
  int sub  = lane >> 5;          // edge slot within a pair (0/1)
  int l32  = lane & 31;          // uint2 (4 halves) position within the 128-col row
  if (node >= N_NODES) return;
  const int* ro = row_off + r * (N_NODES + 1);
  int beg = ro[node], end = ro[node + 1];
  const float2* scp = sc + (size_t)r * N_EDGE;
  const uint2* hp = (const uint2*)h;    // row = 32 uint2 = 128 fp16
  f32x4 acc = (f32x4){0.f, 0.f, 0.f, 0.f};
  int e = beg;
  while (e + 16 <= end) { agg_pairs<8>(scp, hp, e, sub, l32, acc); e += 16; }
  if (e + 8 <= end)     { agg_pairs<4>(scp, hp, e, sub, l32, acc); e += 8; }
  if (e + 4 <= end)     { agg_pairs<2>(scp, hp, e, sub, l32, acc); e += 4; }
  if (e + 2 <= end)     { agg_pairs<1>(scp, hp, e, sub, l32, acc); e += 2; }
  if (e < end && sub == 0) {     // odd tail: slot 0 only
    float2 q = scp[e];
    uint2 v = hp[(size_t)__float_as_int(q.x) * 32 + l32];
    __half2 h0 = *(const __half2*)&v.x;
    __half2 h1 = *(const __half2*)&v.y;
    float2 f0 = __half22float2(h0);
    float2 f1 = __half22float2(h1);
    acc.x = fmaf(q.y, f0.x, acc.x);
    acc.y = fmaf(q.y, f0.y, acc.y);
    acc.z = fmaf(q.y, f1.x, acc.z);
    acc.w = fmaf(q.y, f1.y, acc.w);
  }
  // combine the two edge slots: lanes l and l+32 hold partials for the same 4 cols
  acc.x += __shfl_xor(acc.x, 32);
  acc.y += __shfl_xor(acc.y, 32);
  acc.z += __shfl_xor(acc.z, 32);
  acc.w += __shfl_xor(acc.w, 32);
  // each lane writes 2 of its 4 cols: c = l32*4 + sub*2 (wave covers all 128 cols)
  float a0 = (sub == 0) ? acc.x : acc.z;
  float a1 = (sub == 0) ? acc.y : acc.w;
  __half2 hv = __floats2half2_rn(a0, a1);
  size_t base = (size_t)node * 384 + r * 128 + l32 * 4 + sub * 2;
  *(unsigned*)(agg16 + base) = *(const unsigned*)&hv;
}

// bf16x3 split MFMA GEMM, fp16 A-plane input:
// A arrives as ONE fp16 plane; staging converts fp16 -> bf16 hi/lo IN REGISTERS
// (the ~2^-16 decomposition error is negligible vs fp16's 2^-11). MFMA loop,
// accumulator count, and W path are bit-identical to the proven round-7 kernel.
template<int DO, bool F16OUT>
__launch_bounds__(256)
__global__ void gemm_kernel(const ushort* __restrict__ A16,
                            const ushort* __restrict__ Wh, const ushort* __restrict__ Wl,
                            const float* __restrict__ b, float* __restrict__ out,
                            ushort* __restrict__ out16, int apply_relu) {
  constexpr int K   = 384;
  constexpr int KC  = 32;
  constexpr int NCT = DO / 16;
  constexpr int LDA = 40;
  __shared__ ushort As_hi[128 * LDA], As_lo[128 * LDA];
  __shared__ ushort Bs_hi[DO * LDA],  Bs_lo[DO * LDA];
  int tid  = threadIdx.x;
  int wave = tid >> 6, lane = tid & 63;
  int quad = lane >> 4, m16 = lane & 15;
  int m0 = blockIdx.x * 128;

  f32x4 acc[2][NCT];
  #pragma unroll
  for (int rt = 0; rt < 2; rt++)
    #pragma unroll
    for (int ct = 0; ct < NCT; ct++) acc[rt][ct] = (f32x4){0.f, 0.f, 0.f, 0.f};

  for (int kc = 0; kc < K; kc += KC) {
    __syncthreads();
    // A tile: 128 rows x 32 k. Load 8 fp16 (16B), split to bf16 hi/lo planes.
    #pragma unroll
    for (int it = 0; it < 2; it++) {
      int idx = it * 256 + tid;            // 0..511
      int row = idx >> 2, kq = (idx & 3) * 8;
      uint4 vh = make_uint4(0u, 0u, 0u, 0u), vl = make_uint4(0u, 0u, 0u, 0u);
      if (m0 + row < N_NODES) {
        uint4 va = *(const uint4*)(A16 + (size_t)(m0 + row) * K + kc + kq);
        const ushort* hs = (const ushort*)&va;
        ushort* hh = (ushort*)&vh;
        ushort* ll = (ushort*)&vl;
        #pragma unroll
        for (int j = 0; j < 8; j++) {
          float f = __half2float(*(const __half*)&hs[j]);
          ushort hi = f2bf(f);
          hh[j] = hi;
          ll[j] = f2bf(f - bf2f(hi));
        }
      }
      *(uint4*)&As_hi[row * LDA + kq] = vh;
      *(uint4*)&As_lo[row * LDA + kq] = vl;
    }
    // B tile from pretransposed W: DO rows x 32 k, two planes
    #pragma unroll
    for (int it = 0; it < DO / 64; it++) {
      int idx = it * 256 + tid;            // 0..DO*4-1
      int n = idx >> 2, kq = (idx & 3) * 8;
      *(uint4*)&Bs_hi[n * LDA + kq] = *(const uint4*)(Wh + (size_t)n * K + kc + kq);
      *(uint4*)&Bs_lo[n * LDA + kq] = *(const uint4*)(Wl + (size_t)n * K + kc + kq);
    }
    __syncthreads();

    short8 ah[2], al[2];
    #pragma unroll
    for (int rt = 0; rt < 2; rt++) {
      int m = wave * 32 + rt * 16 + m16;
      ah[rt] = *(const short8*)&As_hi[m * LDA + quad * 8];
      al[rt] = *(const short8*)&As_lo[m * LDA + quad * 8];
    }
    #pragma unroll
    for (int ct = 0; ct < NCT; ct++) {
      int n = ct * 16 + m16;
      short8 bh = *(const short8*)&Bs_hi[n * LDA + quad * 8];
      short8 bl = *(const short8*)&Bs_lo[n * LDA + quad * 8];
      #pragma unroll
      for (int rt = 0; rt < 2; rt++) {
        acc[rt][ct] = __builtin_amdgcn_mfma_f32_16x16x32_bf16(ah[rt], bh, acc[rt][ct], 0, 0, 0);
        acc[rt][ct] = __builtin_amdgcn_mfma_f32_16x16x32_bf16(ah[rt], bl, acc[rt][ct], 0, 0, 0);
        acc[rt][ct] = __builtin_amdgcn_mfma_f32_16x16x32_bf16(al[rt], bh, acc[rt][ct], 0, 0, 0);
      }
    }
  }
  // epilogue: C/D layout col=lane&15, row=quad*4+reg
  #pragma unroll
  for (int ct = 0; ct < NCT; ct++) {
    int col = ct * 16 + m16;
    float bs = b[col] + b[DO + col] + b[2 * DO + col];
    #pragma unroll
    for (int rt = 0; rt < 2; rt++) {
      #pragma unroll
      for (int v = 0; v < 4; v++) {
        int row = m0 + wave * 32 + rt * 16 + quad * 4 + v;
        if (row < N_NODES) {
          float o = acc[rt][ct][v] + bs;
          if (apply_relu) o = fmaxf(o, 0.f);
          if (F16OUT) {
            __half ho = __float2half_rn(o);
            out16[(size_t)row * DO + col] = *(const ushort*)&ho;
          } else {
            out[(size_t)row * DO + col] = o;
          }
        }
      }
    }
  }
}

// ---------------- launch ----------------

extern "C" void kernel_launch(void* const* d_in, const int* in_sizes, int n_in,
                              void* d_out, int out_size, void* d_ws, size_t ws_size,
                              hipStream_t stream) {
  const float* x   = (const float*)d_in[0];
  const int*   src = (const int*)d_in[1];
  const int*   dst = (const int*)d_in[2];
  const float* Wl6[6]; const float* bl[6];
  for (int i = 0; i < 6; i++) { Wl6[i] = (const float*)d_in[3 + 2*i]; bl[i] = (const float*)d_in[4 + 2*i]; }

  // Workspace. Preprocessing scratch (excl, binned, count partials) aliases
  // the agg plane, which is dead until the first agg_kernel write.
  char* ws = (char*)d_ws;
  size_t off = 0;
  auto take = [&](size_t bytes) -> char* {
    char* p = ws + off;
    off = (off + bytes + 255) & ~(size_t)255;
    return p;
  };
  ushort* h16     = (ushort*)take((size_t)N_NODES * 128 * 2);   // fp16 hidden state
  ushort* agg16   = (ushort*)take((size_t)N_NODES * 384 * 2);   // 76.8 MB fp16 A plane
  int*    deg     = (int*)  take((size_t)2 * N_REL * N_NODES * 4);
  int*    deg_out = deg;
  int*    deg_in  = deg + N_REL * N_NODES;
  float*  inv_out = (float*)take((size_t)N_REL * N_NODES * 4);
  float*  inv_in  = (float*)take((size_t)N_REL * N_NODES * 4);
  int*    row_off = (int*)  take((size_t)N_REL * (N_NODES + 1) * 4);
  int*    part    = (int*)  take((size_t)N_REL * NCHUNK * 4);
  int*    boff    = (int*)  take((size_t)CCHUNK * N_REL * NB * 4);   // 469 KB
  float2* s_sc    = (float2*)take((size_t)N_REL * N_EDGE * 8);       // 38.4 MB
  ushort* Wt      = (ushort*)take((size_t)6 * 384 * 128 * 2 * 2);    // hi|lo per layer
  int*    excl    = (int*)agg16;                                     // 1.2 MB
  int2*   binned  = (int2*)((char*)agg16 + (size_t)(2 << 20));       // 38.4 MB @ +2MB
  uint*   cpart   = (uint*)((char*)agg16 + (size_t)(41 << 20));      // 30 MB @ +41MB
  (void)ws_size; (void)in_sizes; (void)n_in; (void)out_size;

  const int nblocks = (N_REL * N_NODES + 255) / 256;

  count_kernel<<<dim3(CCHUNK, N_REL, 2), 1024, 0, stream>>>(src, dst, cpart);
  reduce_kernel<<<(N_REL * CWORDS + 255) / 256, 256, 0, stream>>>(cpart, deg_out, deg_in);
  inv_kernel<<<nblocks, 256, 0, stream>>>(deg_out, deg_in, inv_out, inv_in);
  scan1_kernel<<<dim3(NCHUNK, 3), 1024, 0, stream>>>(deg_in, excl, part);
  scan2_kernel<<<3, 128, 0, stream>>>(part);
  scan3_kernel<<<dim3(NCHUNK + 1, 3), 1024, 0, stream>>>(excl, part, row_off);
  boff_kernel<<<dim3(NB, N_REL), 64, 0, stream>>>(cpart, boff);
  bin2_kernel<<<dim3(CCHUNK, N_REL), 1024, 0, stream>>>(src, dst, row_off, boff, binned);
  scatter2_kernel<<<dim3(NB, N_REL), 256, 0, stream>>>(binned, row_off, inv_out, inv_in, s_sc);

  // x -> fp16 into the h buffer (consumed by layer-0 agg, then overwritten by gemm0)
  convx_kernel<<<(N_NODES * 32 + 255) / 256, 256, 0, stream>>>(x, h16);

  // per-layer weight planes (hi|lo, transposed [DO][384])
  ushort* Wh[6]; ushort* Wlo[6];
  {
    size_t woff = 0;
    for (int L = 0; L < 6; L++) {
      int DOv = (L < 5) ? 128 : 64;
      Wh[L]  = Wt + woff;  woff += (size_t)384 * DOv;
      Wlo[L] = Wt + woff;  woff += (size_t)384 * DOv;
      convw_kernel<<<(384 * DOv + 255) / 256, 256, 0, stream>>>(Wl6[L], Wh[L], Wlo[L], DOv);
    }
  }

  const int mtiles = (N_NODES + 127) / 128;
  const int agg_blocks = (N_NODES + 3) / 4;
  for (int L = 0; L < 6; L++) {
    agg_kernel<<<dim3(agg_blocks, 3), 256, 0, stream>>>(h16, s_sc, row_off, agg16);
    if (L < 5) {
      gemm_kernel<128, true><<<mtiles, 256, 0, stream>>>(agg16, Wh[L], Wlo[L], bl[L],
                                                         nullptr, h16, 1);
    } else {
      gemm_kernel<64, false><<<mtiles, 256, 0, stream>>>(agg16, Wh[L], Wlo[L], bl[L],
                                                         (float*)d_out, nullptr, 0);
    }
  }
}

// Round 11
// 1663.219 us; speedup vs baseline: 1.5429x; 1.0454x over previous
//
#include <hip/hip_runtime.h>
#include <hip/hip_bf16.h>
#include <hip/hip_fp16.h>

constexpr int N_NODES = 100000;
constexpr int N_REL   = 3;
constexpr int N_EDGE  = 1600000;
constexpr int NCHUNK  = (N_NODES + 1023) / 1024;   // 98 (scan chunks)

// atomic-free degree counting geometry
constexpr int CCHUNK = 50;                 // edge chunks  -> 50*3*2 = 300 blocks
constexpr int CH     = N_EDGE / CCHUNK;    // 32000 edges per block
constexpr int SUBN   = 50000;              // nodes per LDS pass (50 KB byte counters)
constexpr int WPP    = SUBN / 4;           // 12500 packed words per pass
constexpr int CWORDS = N_NODES / 4;        // 25000 packed words per (chunk,rel,dir)

// two-level scatter geometry
constexpr int BSH  = 7;                    // bucket = node >> 7 (128 nodes/bucket)
constexpr int BNPB = 1 << BSH;             // 128
constexpr int NB   = (N_NODES + BNPB - 1) / BNPB;   // 782 buckets

typedef __attribute__((ext_vector_type(8))) short short8;
typedef __attribute__((ext_vector_type(4))) float f32x4;

__device__ inline ushort f2bf(float x) {            // round-to-nearest-even bf16
  unsigned u = __float_as_uint(x);
  unsigned r = u + 0x7FFFu + ((u >> 16) & 1u);
  return (ushort)(r >> 16);
}
__device__ inline float bf2f(ushort h) { return __uint_as_float(((unsigned)h) << 16); }

// ---------------- graph preprocessing (atomic-free counting) ----------------

// Byte-packed LDS histogram: 4 node-counters per int word. 50KB LDS covers
// 50K nodes -> 2 passes over this block's 32K-edge chunk. 300 blocks.
__global__ __launch_bounds__(1024)
void count_kernel(const int* __restrict__ src, const int* __restrict__ dst,
                  uint* __restrict__ part) {
  int c = blockIdx.x, r = blockIdx.y, dir = blockIdx.z;
  const int* ids = (dir ? dst : src) + (size_t)r * N_EDGE + (size_t)c * CH;
  uint* p = part + ((size_t)(c * N_REL + r) * 2 + dir) * CWORDS;
  __shared__ uint hist[WPP];
  #pragma unroll
  for (int pass = 0; pass < 2; pass++) {
    int base = pass * SUBN;
    for (int i = threadIdx.x; i < WPP; i += 1024) hist[i] = 0u;
    __syncthreads();
    for (int e = (int)threadIdx.x; e < CH; e += 1024) {
      int ln = ids[e] - base;
      if ((unsigned)ln < (unsigned)SUBN)
        atomicAdd(&hist[ln >> 2], 1u << ((ln & 3) * 8));
    }
    __syncthreads();
    for (int i = threadIdx.x; i < WPP; i += 1024) p[pass * WPP + i] = hist[i];
    __syncthreads();
  }
}

// SWAR reduce of packed byte partials: 16-bit lanes (50*255 = 12750 < 65536).
__global__ void reduce_kernel(const uint* __restrict__ part,
                              int* __restrict__ deg_out, int* __restrict__ deg_in) {
  int i = blockIdx.x * 256 + threadIdx.x;       // over 3*CWORDS
  if (i >= N_REL * CWORDS) return;
  int r = i / CWORDS, w = i % CWORDS;
  uint aoe = 0, aoo = 0, aie = 0, aio = 0;
  for (int c = 0; c < CCHUNK; c++) {
    uint vo = part[((size_t)(c * N_REL + r) * 2 + 0) * CWORDS + w];
    uint vi = part[((size_t)(c * N_REL + r) * 2 + 1) * CWORDS + w];
    aoe += vo & 0x00FF00FFu; aoo += (vo >> 8) & 0x00FF00FFu;
    aie += vi & 0x00FF00FFu; aio += (vi >> 8) & 0x00FF00FFu;
  }
  int4 dout = make_int4((int)(aoe & 0xFFFFu), (int)(aoo & 0xFFFFu),
                        (int)(aoe >> 16),     (int)(aoo >> 16));
  int4 din  = make_int4((int)(aie & 0xFFFFu), (int)(aio & 0xFFFFu),
                        (int)(aie >> 16),     (int)(aio >> 16));
  *(int4*)&deg_out[(size_t)r * N_NODES + w * 4] = dout;
  *(int4*)&deg_in [(size_t)r * N_NODES + w * 4] = din;
}

__global__ void inv_kernel(const int* __restrict__ deg_out, const int* __restrict__ deg_in,
                           float* __restrict__ inv_out, float* __restrict__ inv_in) {
  int i = blockIdx.x * blockDim.x + threadIdx.x;
  if (i >= N_REL * N_NODES) return;
  inv_out[i] = rsqrtf(fmaxf((float)deg_out[i], 1.0f));
  inv_in[i]  = rsqrtf(fmaxf((float)deg_in[i],  1.0f));
}

__global__ void scan1_kernel(const int* __restrict__ deg_in, int* __restrict__ excl,
                             int* __restrict__ part) {
  int r = blockIdx.y;
  int i = blockIdx.x * 1024 + threadIdx.x;
  int v = (i < N_NODES) ? deg_in[r * N_NODES + i] : 0;
  __shared__ int sm[1024];
  sm[threadIdx.x] = v;
  __syncthreads();
  for (int off = 1; off < 1024; off <<= 1) {
    int t = (threadIdx.x >= (unsigned)off) ? sm[threadIdx.x - off] : 0;
    __syncthreads();
    sm[threadIdx.x] += t;
    __syncthreads();
  }
  if (i < N_NODES) excl[r * N_NODES + i] = sm[threadIdx.x] - v;
  if (threadIdx.x == 1023) part[r * NCHUNK + blockIdx.x] = sm[1023];
}

__global__ void scan2_kernel(int* __restrict__ part) {
  int r = blockIdx.x;
  int* p = part + r * NCHUNK;
  __shared__ int sm[128];
  int tid = threadIdx.x;
  int v = (tid < NCHUNK) ? p[tid] : 0;
  sm[tid] = v;
  __syncthreads();
  for (int off = 1; off < 128; off <<= 1) {
    int t = (tid >= off) ? sm[tid - off] : 0;
    __syncthreads();
    sm[tid] += t;
    __syncthreads();
  }
  if (tid < NCHUNK) p[tid] = sm[tid] - v;
}

__global__ void scan3_kernel(const int* __restrict__ excl, const int* __restrict__ part,
                             int* __restrict__ row_off) {
  int r = blockIdx.y;
  int i = blockIdx.x * 1024 + threadIdx.x;
  if (i < N_NODES) row_off[r * (N_NODES + 1) + i] = excl[r * N_NODES + i] + part[r * NCHUNK + (i >> 10)];
  if (i == N_NODES) row_off[r * (N_NODES + 1) + N_NODES] = N_EDGE;
}

// ---------------- two-level scatter, fully atomic-free level 1 ----------------

__global__ __launch_bounds__(64)
void boff_kernel(const uint* __restrict__ cpart, int* __restrict__ boff) {
  int b = blockIdx.x, r = blockIdx.y;
  int lane = threadIdx.x;                     // 0..63 (lanes 32-63 duplicate 0-31)
  __shared__ int cnt_l[CCHUNK];
  for (int c = 0; c < CCHUNK; c++) {
    int w = b * 32 + (lane & 31);
    uint v = 0;
    if (w < CWORDS)
      v = cpart[((size_t)(c * N_REL + r) * 2 + 1) * CWORDS + w];   // dir=1: dst
    int s = (int)((v & 0xFFu) + ((v >> 8) & 0xFFu) + ((v >> 16) & 0xFFu) + (v >> 24));
    #pragma unroll
    for (int k = 16; k >= 1; k >>= 1) s += __shfl_xor(s, k);
    if (lane == 0) cnt_l[c] = s;
  }
  __syncthreads();
  if (lane == 0) {
    int run = 0;
    for (int c = 0; c < CCHUNK; c++) { int t = cnt_l[c]; cnt_l[c] = run; run += t; }
  }
  __syncthreads();
  for (int c = lane; c < CCHUNK; c += 64)
    boff[((size_t)c * N_REL + r) * NB + b] = cnt_l[c];
}

// Level 1: packed 4B records (dlow7<<17 | src17). Halves bin write traffic.
__global__ __launch_bounds__(1024)
void bin2_kernel(const int* __restrict__ src, const int* __restrict__ dst,
                 const int* __restrict__ row_off, const int* __restrict__ boff,
                 uint* __restrict__ binned) {
  int c = blockIdx.x, r = blockIdx.y;
  __shared__ int cur[NB];
  for (int j = threadIdx.x; j < NB; j += 1024)
    cur[j] = row_off[r * (N_NODES + 1) + (j << BSH)] + boff[((size_t)c * N_REL + r) * NB + j];
  __syncthreads();
  const int* sp = src + (size_t)r * N_EDGE + (size_t)c * CH;
  const int* dp = dst + (size_t)r * N_EDGE + (size_t)c * CH;
  uint* bp = binned + (size_t)r * N_EDGE;
  for (int e = (int)threadIdx.x; e < CH; e += 1024) {
    int s = sp[e], d = dp[e];
    int slot = atomicAdd(&cur[d >> BSH], 1);
    bp[slot] = ((uint)(d & (BNPB - 1)) << 17) | (uint)s;
  }
}

// Level 2: unpack, compute coef from L2-resident inv arrays, place via LDS
// cursor, write packed sc record (coef_fp15<<17 | src17) — 4 B/edge.
__global__ __launch_bounds__(256)
void scatter2_kernel(const uint* __restrict__ binned, const int* __restrict__ row_off,
                     const float* __restrict__ inv_out, const float* __restrict__ inv_in,
                     uint* __restrict__ sorted_sc) {
  int b = blockIdx.x, r = blockIdx.y;
  int node0 = b << BSH;
  int node1 = min(node0 + BNPB, N_NODES);
  const int* ro = row_off + r * (N_NODES + 1);
  int base = ro[node0];
  int m    = ro[node1] - base;
  __shared__ int cur[BNPB];
  for (int j = threadIdx.x; j < node1 - node0; j += 256)
    cur[j] = ro[node0 + j] - base;
  __syncthreads();
  const uint* bp = binned + (size_t)r * N_EDGE + base;
  uint* op = sorted_sc + (size_t)r * N_EDGE + base;
  const float* ivo = inv_out + r * N_NODES;
  const float* ivi = inv_in  + r * N_NODES;
  for (int i = threadIdx.x; i < m; i += 256) {
    uint rec = bp[i];
    int s    = (int)(rec & 0x1FFFFu);
    int dlow = (int)((rec >> 17) & (uint)(BNPB - 1));
    int d    = node0 + dlow;
    int pos  = atomicAdd(&cur[dlow], 1);
    float coef = ivo[s] * ivi[d];
    __half ch = __float2half_rn(coef);
    uint cb = (uint)(*(const ushort*)&ch) & 0x7FFFu;   // coef > 0: drop sign bit
    op[pos] = (cb << 17) | (uint)s;
  }
}

// per-layer weight preconvert: W[k][c] fp32 -> transposed hi/lo bf16 planes Wt[c][k]
__global__ void convw_kernel(const float* __restrict__ W, ushort* __restrict__ Wh,
                             ushort* __restrict__ Wl, int DOv) {
  int idx = blockIdx.x * 256 + threadIdx.x;
  if (idx >= 384 * DOv) return;
  int k = idx / DOv, c = idx % DOv;
  float v = W[idx];
  ushort hh = f2bf(v);
  Wh[c * 384 + k] = hh;
  Wl[c * 384 + k] = f2bf(v - bf2f(hh));
}

// x fp32 [N][128] -> fp16 [N][128]
__global__ void convx_kernel(const float* __restrict__ x, ushort* __restrict__ x16) {
  int i = blockIdx.x * 256 + threadIdx.x;      // one float4 group each
  if (i >= N_NODES * 32) return;
  f32x4 v = ((const f32x4*)x)[i];
  __half2 h0 = __floats2half2_rn(v.x, v.y);
  __half2 h1 = __floats2half2_rn(v.z, v.w);
  uint2 o;
  o.x = *(const unsigned*)&h0;
  o.y = *(const unsigned*)&h1;
  ((uint2*)x16)[i] = o;
}

// ---------------- per-layer kernels ----------------

// Gather-first: acc[n][r*128+c] = sum coef_e * h[src_e][c] (fp32 accumulate),
// h stored fp16, sc records packed to 4 B (coef fp15 | src 17b). Output: one
// fp16 plane. agg runs at the ~3.5 TB/s L2-miss service ceiling; packed sc
// shaves 19 MB/dispatch off that stream.
template<int P>
__device__ inline void agg_pairs(const uint* __restrict__ scp, const uint2* __restrict__ hp,
                                 int e, int sub, int l32, f32x4& acc) {
  uint q[P];
  #pragma unroll
  for (int j = 0; j < P; j++) q[j] = scp[e + 2 * j + sub];
  uint2 v[P];
  #pragma unroll
  for (int j = 0; j < P; j++) v[j] = hp[(size_t)(q[j] & 0x1FFFFu) * 32 + l32];
  #pragma unroll
  for (int j = 0; j < P; j++) {
    ushort cb = (ushort)(q[j] >> 17);
    float cf = __half2float(*(const __half*)&cb);
    __half2 h0 = *(const __half2*)&v[j].x;
    __half2 h1 = *(const __half2*)&v[j].y;
    float2 f0 = __half22float2(h0);
    float2 f1 = __half22float2(h1);
    acc.x = fmaf(cf, f0.x, acc.x);
    acc.y = fmaf(cf, f0.y, acc.y);
    acc.z = fmaf(cf, f1.x, acc.z);
    acc.w = fmaf(cf, f1.y, acc.w);
  }
}

__launch_bounds__(256)
__global__ void agg_kernel(const ushort* __restrict__ h, const uint* __restrict__ sc,
                           const int* __restrict__ row_off,
                           ushort* __restrict__ agg16) {
  int r    = blockIdx.y;
  int node = blockIdx.x * 4 + ((int)threadIdx.x >> 6);
  int lane = (int)threadIdx.x & 63;
  int sub  = lane >> 5;          // edge slot within a pair (0/1)
  int l32  = lane & 31;          // uint2 (4 halves) position within the 128-col row
  if (node >= N_NODES) return;
  const int* ro = row_off + r * (N_NODES + 1);
  int beg = ro[node], end = ro[node + 1];
  const uint* scp = sc + (size_t)r * N_EDGE;
  const uint2* hp = (const uint2*)h;    // row = 32 uint2 = 128 fp16
  f32x4 acc = (f32x4){0.f, 0.f, 0.f, 0.f};
  int e = beg;
  while (e + 16 <= end) { agg_pairs<8>(scp, hp, e, sub, l32, acc); e += 16; }
  if (e + 8 <= end)     { agg_pairs<4>(scp, hp, e, sub, l32, acc); e += 8; }
  if (e + 4 <= end)     { agg_pairs<2>(scp, hp, e, sub, l32, acc); e += 4; }
  if (e + 2 <= end)     { agg_pairs<1>(scp, hp, e, sub, l32, acc); e += 2; }
  if (e < end && sub == 0) {     // odd tail: slot 0 only
    uint q = scp[e];
    uint2 v = hp[(size_t)(q & 0x1FFFFu) * 32 + l32];
    ushort cb = (ushort)(q >> 17);
    float cf = __half2float(*(const __half*)&cb);
    __half2 h0 = *(const __half2*)&v.x;
    __half2 h1 = *(const __half2*)&v.y;
    float2 f0 = __half22float2(h0);
    float2 f1 = __half22float2(h1);
    acc.x = fmaf(cf, f0.x, acc.x);
    acc.y = fmaf(cf, f0.y, acc.y);
    acc.z = fmaf(cf, f1.x, acc.z);
    acc.w = fmaf(cf, f1.y, acc.w);
  }
  // combine the two edge slots: lanes l and l+32 hold partials for the same 4 cols
  acc.x += __shfl_xor(acc.x, 32);
  acc.y += __shfl_xor(acc.y, 32);
  acc.z += __shfl_xor(acc.z, 32);
  acc.w += __shfl_xor(acc.w, 32);
  // each lane writes 2 of its 4 cols: c = l32*4 + sub*2 (wave covers all 128 cols)
  float a0 = (sub == 0) ? acc.x : acc.z;
  float a1 = (sub == 0) ? acc.y : acc.w;
  __half2 hv = __floats2half2_rn(a0, a1);
  size_t base = (size_t)node * 384 + r * 128 + l32 * 4 + sub * 2;
  *(unsigned*)(agg16 + base) = *(const unsigned*)&hv;
}

// bf16x3 split MFMA GEMM, fp16 A-plane input:
// A arrives as ONE fp16 plane; staging converts fp16 -> bf16 hi/lo IN REGISTERS.
// MFMA loop, accumulator count, and W path identical to the proven round-7 kernel.
template<int DO, bool F16OUT>
__launch_bounds__(256)
__global__ void gemm_kernel(const ushort* __restrict__ A16,
                            const ushort* __restrict__ Wh, const ushort* __restrict__ Wl,
                            const float* __restrict__ b, float* __restrict__ out,
                            ushort* __restrict__ out16, int apply_relu) {
  constexpr int K   = 384;
  constexpr int KC  = 32;
  constexpr int NCT = DO / 16;
  constexpr int LDA = 40;
  __shared__ ushort As_hi[128 * LDA], As_lo[128 * LDA];
  __shared__ ushort Bs_hi[DO * LDA],  Bs_lo[DO * LDA];
  int tid  = threadIdx.x;
  int wave = tid >> 6, lane = tid & 63;
  int quad = lane >> 4, m16 = lane & 15;
  int m0 = blockIdx.x * 128;

  f32x4 acc[2][NCT];
  #pragma unroll
  for (int rt = 0; rt < 2; rt++)
    #pragma unroll
    for (int ct = 0; ct < NCT; ct++) acc[rt][ct] = (f32x4){0.f, 0.f, 0.f, 0.f};

  for (int kc = 0; kc < K; kc += KC) {
    __syncthreads();
    // A tile: 128 rows x 32 k. Load 8 fp16 (16B), split to bf16 hi/lo planes.
    #pragma unroll
    for (int it = 0; it < 2; it++) {
      int idx = it * 256 + tid;            // 0..511
      int row = idx >> 2, kq = (idx & 3) * 8;
      uint4 vh = make_uint4(0u, 0u, 0u, 0u), vl = make_uint4(0u, 0u, 0u, 0u);
      if (m0 + row < N_NODES) {
        uint4 va = *(const uint4*)(A16 + (size_t)(m0 + row) * K + kc + kq);
        const ushort* hs = (const ushort*)&va;
        ushort* hh = (ushort*)&vh;
        ushort* ll = (ushort*)&vl;
        #pragma unroll
        for (int j = 0; j < 8; j++) {
          float f = __half2float(*(const __half*)&hs[j]);
          ushort hi = f2bf(f);
          hh[j] = hi;
          ll[j] = f2bf(f - bf2f(hi));
        }
      }
      *(uint4*)&As_hi[row * LDA + kq] = vh;
      *(uint4*)&As_lo[row * LDA + kq] = vl;
    }
    // B tile from pretransposed W: DO rows x 32 k, two planes
    #pragma unroll
    for (int it = 0; it < DO / 64; it++) {
      int idx = it * 256 + tid;            // 0..DO*4-1
      int n = idx >> 2, kq = (idx & 3) * 8;
      *(uint4*)&Bs_hi[n * LDA + kq] = *(const uint4*)(Wh + (size_t)n * K + kc + kq);
      *(uint4*)&Bs_lo[n * LDA + kq] = *(const uint4*)(Wl + (size_t)n * K + kc + kq);
    }
    __syncthreads();

    short8 ah[2], al[2];
    #pragma unroll
    for (int rt = 0; rt < 2; rt++) {
      int m = wave * 32 + rt * 16 + m16;
      ah[rt] = *(const short8*)&As_hi[m * LDA + quad * 8];
      al[rt] = *(const short8*)&As_lo[m * LDA + quad * 8];
    }
    #pragma unroll
    for (int ct = 0; ct < NCT; ct++) {
      int n = ct * 16 + m16;
      short8 bh = *(const short8*)&Bs_hi[n * LDA + quad * 8];
      short8 bl = *(const short8*)&Bs_lo[n * LDA + quad * 8];
      #pragma unroll
      for (int rt = 0; rt < 2; rt++) {
        acc[rt][ct] = __builtin_amdgcn_mfma_f32_16x16x32_bf16(ah[rt], bh, acc[rt][ct], 0, 0, 0);
        acc[rt][ct] = __builtin_amdgcn_mfma_f32_16x16x32_bf16(ah[rt], bl, acc[rt][ct], 0, 0, 0);
        acc[rt][ct] = __builtin_amdgcn_mfma_f32_16x16x32_bf16(al[rt], bh, acc[rt][ct], 0, 0, 0);
      }
    }
  }
  // epilogue: C/D layout col=lane&15, row=quad*4+reg
  #pragma unroll
  for (int ct = 0; ct < NCT; ct++) {
    int col = ct * 16 + m16;
    float bs = b[col] + b[DO + col] + b[2 * DO + col];
    #pragma unroll
    for (int rt = 0; rt < 2; rt++) {
      #pragma unroll
      for (int v = 0; v < 4; v++) {
        int row = m0 + wave * 32 + rt * 16 + quad * 4 + v;
        if (row < N_NODES) {
          float o = acc[rt][ct][v] + bs;
          if (apply_relu) o = fmaxf(o, 0.f);
          if (F16OUT) {
            __half ho = __float2half_rn(o);
            out16[(size_t)row * DO + col] = *(const ushort*)&ho;
          } else {
            out[(size_t)row * DO + col] = o;
          }
        }
      }
    }
  }
}

// ---------------- launch ----------------

extern "C" void kernel_launch(void* const* d_in, const int* in_sizes, int n_in,
                              void* d_out, int out_size, void* d_ws, size_t ws_size,
                              hipStream_t stream) {
  const float* x   = (const float*)d_in[0];
  const int*   src = (const int*)d_in[1];
  const int*   dst = (const int*)d_in[2];
  const float* Wl6[6]; const float* bl[6];
  for (int i = 0; i < 6; i++) { Wl6[i] = (const float*)d_in[3 + 2*i]; bl[i] = (const float*)d_in[4 + 2*i]; }

  // Workspace. Preprocessing scratch (excl, binned, count partials) aliases
  // the agg plane, which is dead until the first agg_kernel write.
  char* ws = (char*)d_ws;
  size_t off = 0;
  auto take = [&](size_t bytes) -> char* {
    char* p = ws + off;
    off = (off + bytes + 255) & ~(size_t)255;
    return p;
  };
  ushort* h16     = (ushort*)take((size_t)N_NODES * 128 * 2);   // fp16 hidden state
  ushort* agg16   = (ushort*)take((size_t)N_NODES * 384 * 2);   // 76.8 MB fp16 A plane
  int*    deg     = (int*)  take((size_t)2 * N_REL * N_NODES * 4);
  int*    deg_out = deg;
  int*    deg_in  = deg + N_REL * N_NODES;
  float*  inv_out = (float*)take((size_t)N_REL * N_NODES * 4);
  float*  inv_in  = (float*)take((size_t)N_REL * N_NODES * 4);
  int*    row_off = (int*)  take((size_t)N_REL * (N_NODES + 1) * 4);
  int*    part    = (int*)  take((size_t)N_REL * NCHUNK * 4);
  int*    boff    = (int*)  take((size_t)CCHUNK * N_REL * NB * 4);   // 469 KB
  uint*   s_sc    = (uint*) take((size_t)N_REL * N_EDGE * 4);        // 19.2 MB packed
  ushort* Wt      = (ushort*)take((size_t)6 * 384 * 128 * 2 * 2);    // hi|lo per layer
  int*    excl    = (int*)agg16;                                     // 1.2 MB
  uint*   binned  = (uint*)((char*)agg16 + (size_t)(2 << 20));       // 19.2 MB @ +2MB
  uint*   cpart   = (uint*)((char*)agg16 + (size_t)(22 << 20));      // 30 MB @ +22MB
  (void)ws_size; (void)in_sizes; (void)n_in; (void)out_size;

  const int nblocks = (N_REL * N_NODES + 255) / 256;

  count_kernel<<<dim3(CCHUNK, N_REL, 2), 1024, 0, stream>>>(src, dst, cpart);
  reduce_kernel<<<(N_REL * CWORDS + 255) / 256, 256, 0, stream>>>(cpart, deg_out, deg_in);
  inv_kernel<<<nblocks, 256, 0, stream>>>(deg_out, deg_in, inv_out, inv_in);
  scan1_kernel<<<dim3(NCHUNK, 3), 1024, 0, stream>>>(deg_in, excl, part);
  scan2_kernel<<<3, 128, 0, stream>>>(part);
  scan3_kernel<<<dim3(NCHUNK + 1, 3), 1024, 0, stream>>>(excl, part, row_off);
  boff_kernel<<<dim3(NB, N_REL), 64, 0, stream>>>(cpart, boff);
  bin2_kernel<<<dim3(CCHUNK, N_REL), 1024, 0, stream>>>(src, dst, row_off, boff, binned);
  scatter2_kernel<<<dim3(NB, N_REL), 256, 0, stream>>>(binned, row_off, inv_out, inv_in, s_sc);

  // x -> fp16 into the h buffer (consumed by layer-0 agg, then overwritten by gemm0)
  convx_kernel<<<(N_NODES * 32 + 255) / 256, 256, 0, stream>>>(x, h16);

  // per-layer weight planes (hi|lo, transposed [DO][384])
  ushort* Wh[6]; ushort* Wlo[6];
  {
    size_t woff = 0;
    for (int L = 0; L < 6; L++) {
      int DOv = (L < 5) ? 128 : 64;
      Wh[L]  = Wt + woff;  woff += (size_t)384 * DOv;
      Wlo[L] = Wt + woff;  woff += (size_t)384 * DOv;
      convw_kernel<<<(384 * DOv + 255) / 256, 256, 0, stream>>>(Wl6[L], Wh[L], Wlo[L], DOv);
    }
  }

  const int mtiles = (N_NODES + 127) / 128;
  const int agg_blocks = (N_NODES + 3) / 4;
  for (int L = 0; L < 6; L++) {
    agg_kernel<<<dim3(agg_blocks, 3), 256, 0, stream>>>(h16, s_sc, row_off, agg16);
    if (L < 5) {
      gemm_kernel<128, true><<<mtiles, 256, 0, stream>>>(agg16, Wh[L], Wlo[L], bl[L],
                                                         nullptr, h16, 1);
    } else {
      gemm_kernel<64, false><<<mtiles, 256, 0, stream>>>(agg16, Wh[L], Wlo[L], bl[L],
                                                         (float*)d_out, nullptr, 0);
    }
  }
}